// Round 10
// baseline (1041.104 us; speedup 1.0000x reference)
//
#include <hip/hip_runtime.h>

#define NN 100000      // N_NODES
#define NE 3200000     // N_EDGES
#define NF 128         // N_F
#define NH 128         // HIDDEN
#define NP 8           // N_PRED
#define NG 64          // N_GRAPHS

#define CS 16000       // bins per chunk (64 KB LDS as u32/f32)
#define NC 7           // ceil(100000/16000)
#define NW 64          // edge slices
#define ES (NE / NW)   // 50000 edges per slice (divisible by 8)

#define PT 64          // k_pool node tile
#define GP 1024        // k_pool grid

#define NPASS 4        // hop graph-chunks (16 graphs each; 3.2 MB Qin chunk < 4 MB XCD L2)
#define HB 25000       // hop blocks per pass (4 dest-waves each)

#define SCAN_B 1024
#define SCAN_NBLK 98   // ceil(100000/1024)

// f32 -> bf16 (RNE), bf16 -> f32 (shift)
__device__ __forceinline__ unsigned short f2bf(float f) {
    unsigned u = __float_as_uint(f);
    return (unsigned short)((u + 0x7fffu + ((u >> 16) & 1u)) >> 16);
}
__device__ __forceinline__ float bf2f(unsigned short b) {
    return __uint_as_float((unsigned)b << 16);
}

// ---------------- init: cnt, psum ----------------
__global__ void k_init(float* __restrict__ cnt, float* __restrict__ psum) {
    int i = blockIdx.x * blockDim.x + threadIdx.x;
    if (i < NG) cnt[i] = 0.0f;
    if (i < NG * NH) psum[i] = 0.0f;
}

// ---------------- row histogram: H[w][r] via LDS, 8-edge vector loads ----------------
__global__ __launch_bounds__(256) void k_hist(const int* __restrict__ row,
                                              unsigned* __restrict__ H) {
    __shared__ unsigned hist[CS];
    int w = blockIdx.x % NW, c = blockIdx.x / NW;
    int rbase = c * CS;
    int nb = (rbase + CS <= NN) ? CS : (NN - rbase);
    for (int i = threadIdx.x; i < nb; i += 256) hist[i] = 0u;
    __syncthreads();
    const int4* r4 = (const int4*)(row + (size_t)w * ES);
    for (int i = threadIdx.x; i < ES / 8; i += 256) {
        int4 a = r4[2 * i], b = r4[2 * i + 1];
        int rs[8] = {a.x, a.y, a.z, a.w, b.x, b.y, b.z, b.w};
#pragma unroll
        for (int j = 0; j < 8; ++j) {
            unsigned rr = (unsigned)(rs[j] - rbase);
            if (rr < (unsigned)nb) atomicAdd(&hist[rr], 1u);
        }
    }
    __syncthreads();
    for (int i = threadIdx.x; i < nb; i += 256) H[(size_t)w * NN + rbase + i] = hist[i];
}

// ---------------- weighted col histogram: Hd[w][c] via LDS, vector loads ----------------
__global__ __launch_bounds__(256) void k_deg_hist(const int* __restrict__ col,
                                                  const float* __restrict__ wt,
                                                  float* __restrict__ Hd) {
    __shared__ float dh[CS];
    int w = blockIdx.x % NW, c = blockIdx.x / NW;
    int rbase = c * CS;
    int nb = (rbase + CS <= NN) ? CS : (NN - rbase);
    for (int i = threadIdx.x; i < nb; i += 256) dh[i] = 0.0f;
    __syncthreads();
    const int4*   c4 = (const int4*)(col + (size_t)w * ES);
    const float4* w4 = (const float4*)(wt + (size_t)w * ES);
    for (int i = threadIdx.x; i < ES / 8; i += 256) {
        int4 a = c4[2 * i], b = c4[2 * i + 1];
        float4 wa = w4[2 * i], wb = w4[2 * i + 1];
        int cc[8] = {a.x, a.y, a.z, a.w, b.x, b.y, b.z, b.w};
        float ww[8] = {wa.x, wa.y, wa.z, wa.w, wb.x, wb.y, wb.z, wb.w};
#pragma unroll
        for (int j = 0; j < 8; ++j) {
            unsigned rr = (unsigned)(cc[j] - rbase);
            if (rr < (unsigned)nb) atomicAdd(&dh[rr], ww[j]);
        }
    }
    __syncthreads();
    for (int i = threadIdx.x; i < nb; i += 256) Hd[(size_t)w * NN + rbase + i] = dh[i];
}

// ---------------- per-graph node counts ----------------
__global__ void k_cnt(const int* __restrict__ batch, float* __restrict__ cnt) {
    __shared__ float c[NG];
    int t = threadIdx.x;
    if (t < NG) c[t] = 0.0f;
    __syncthreads();
    int i = blockIdx.x * blockDim.x + t;
    if (i < NN) atomicAdd(&c[batch[i]], 1.0f);
    __syncthreads();
    if (t < NG && c[t] != 0.0f) atomicAdd(&cnt[t], c[t]);
}

// ---------------- reduce slices: rcnt[r] = sum_w H, dinv[r] = rsqrt(1 + sum_w Hd) ----------------
__global__ void k_reduce(const unsigned* __restrict__ H, const float* __restrict__ Hd,
                         int* __restrict__ rcnt, float* __restrict__ dinv) {
    int r = blockIdx.x * blockDim.x + threadIdx.x;
    if (r >= NN) return;
    unsigned s = 0;
    float d = 1.0f;   // self-loop weight
#pragma unroll
    for (int w = 0; w < NW; ++w) {
        s += H[(size_t)w * NN + r];
        d += Hd[(size_t)w * NN + r];
    }
    rcnt[r] = (int)s;
    dinv[r] = rsqrtf(d);
}

// ---------------- scan pass 1 ----------------
__global__ __launch_bounds__(SCAN_B) void k_scan1(const int* __restrict__ rcnt,
                                                  int* __restrict__ px,
                                                  int* __restrict__ bsum) {
    __shared__ int s[SCAN_B];
    int t = threadIdx.x;
    int i = blockIdx.x * SCAN_B + t;
    int v = (i < NN) ? rcnt[i] : 0;
    s[t] = v;
    __syncthreads();
    for (int off = 1; off < SCAN_B; off <<= 1) {
        int x = (t >= off) ? s[t - off] : 0;
        __syncthreads();
        s[t] += x;
        __syncthreads();
    }
    px[i] = s[t] - v;
    if (t == SCAN_B - 1) bsum[blockIdx.x] = s[t];
}

// ---------------- scan pass 2 ----------------
__global__ void k_scan2(const int* __restrict__ bsum, int* __restrict__ bofs) {
    if (threadIdx.x == 0) {
        int acc = 0;
        for (int b = 0; b < SCAN_NBLK; ++b) { bofs[b] = acc; acc += bsum[b]; }
    }
}

// ---------------- scan pass 3: rowptr ----------------
__global__ void k_scan3(const int* __restrict__ px, const int* __restrict__ bofs,
                        int* __restrict__ rowptr) {
    int i = blockIdx.x * blockDim.x + threadIdx.x;
    if (i > NN) return;
    rowptr[i] = px[i] + bofs[i >> 10];
}

// ---------------- H -> per-(row,slice) base offsets (in place) ----------------
__global__ void k_base(const int* __restrict__ rowptr, unsigned* __restrict__ H) {
    int r = blockIdx.x * blockDim.x + threadIdx.x;
    if (r >= NN) return;
    unsigned acc = (unsigned)rowptr[r];
#pragma unroll
    for (int w = 0; w < NW; ++w) {
        unsigned v = H[(size_t)w * NN + r];
        H[(size_t)w * NN + r] = acc;
        acc += v;
    }
}

// ---------------- stable counting-sort scatter, vector loads ----------------
// pack[pos] = (srcoff = src*32, nrm f32)  -- srcoff is the byte offset of the
// src row in a 16-graph bf16 chunk (32 B rows).
__global__ __launch_bounds__(256) void k_sort(const int* __restrict__ row,
                                              const int* __restrict__ col,
                                              const float* __restrict__ wt,
                                              const unsigned* __restrict__ B,
                                              const float* __restrict__ dinv,
                                              float2* __restrict__ pack) {
    __shared__ unsigned basel[CS];
    int w = blockIdx.x % NW, c = blockIdx.x / NW;
    int rbase = c * CS;
    int nb = (rbase + CS <= NN) ? CS : (NN - rbase);
    for (int i = threadIdx.x; i < nb; i += 256)
        basel[i] = B[(size_t)w * NN + rbase + i];
    __syncthreads();
    const int4*   r4 = (const int4*)(row + (size_t)w * ES);
    const int4*   c4 = (const int4*)(col + (size_t)w * ES);
    const float4* w4 = (const float4*)(wt + (size_t)w * ES);
    for (int i = threadIdx.x; i < ES / 8; i += 256) {
        int4 ra = r4[2 * i], rb = r4[2 * i + 1];
        int4 ca = c4[2 * i], cb = c4[2 * i + 1];
        float4 wa = w4[2 * i], wb = w4[2 * i + 1];
        int rs[8] = {ra.x, ra.y, ra.z, ra.w, rb.x, rb.y, rb.z, rb.w};
        int cs[8] = {ca.x, ca.y, ca.z, ca.w, cb.x, cb.y, cb.z, cb.w};
        float ww[8] = {wa.x, wa.y, wa.z, wa.w, wb.x, wb.y, wb.z, wb.w};
#pragma unroll
        for (int j = 0; j < 8; ++j) {
            unsigned rr = (unsigned)(rs[j] - rbase);
            if (rr < (unsigned)nb) {
                unsigned pos = atomicAdd(&basel[rr], 1u);
                pack[pos] = make_float2(__int_as_float(cs[j] << 5),
                                        dinv[rs[j]] * ww[j] * dinv[cs[j]]);
            }
        }
    }
}

// ---------------- hop 1 (chunked bf16 out): Q[c][n][j] ----------------
__global__ void k_q1_gather(const int* __restrict__ rowptr, const float2* __restrict__ pack,
                            const int* __restrict__ batch, const float* __restrict__ dinv,
                            unsigned short* __restrict__ Q) {
    int wid = (blockIdx.x * blockDim.x + threadIdx.x) >> 6;
    int lane = threadIdx.x & 63;
    if (wid >= NN) return;
    int beg = rowptr[wid], end = rowptr[wid + 1];
    float d = dinv[wid];
    float acc = (batch[wid] == lane) ? d * d : 0.0f;
    const char* bc8 = (const char*)batch;
    const unsigned long long* pk = (const unsigned long long*)pack;
    int e = beg;
    for (; e + 8 <= end; e += 8) {
        unsigned long long p[8];
#pragma unroll
        for (int j = 0; j < 8; ++j)
            p[j] = __builtin_nontemporal_load(pk + e + j);
        int b[8];
#pragma unroll
        for (int j = 0; j < 8; ++j)
            b[j] = *(const int*)(bc8 + (((unsigned)p[j]) >> 3));
#pragma unroll
        for (int j = 0; j < 8; ++j)
            acc += (b[j] == lane) ? __uint_as_float((unsigned)(p[j] >> 32)) : 0.0f;
    }
    for (; e < end; ++e) {
        unsigned long long p = pk[e];
        acc += (*(const int*)(bc8 + (((unsigned)p) >> 3)) == lane)
               ? __uint_as_float((unsigned)(p >> 32)) : 0.0f;
    }
    // chunked store: chunk = lane>>4, j = lane&15
    Q[(size_t)(lane >> 4) * (NN * 16) + wid * 16 + (lane & 15)] = f2bf(acc);
}

// ---------------- hops 2,3: phased 16-graph chunks ----------------
// pass = blockIdx.x / HB (dispatch-ordered => L2 phases through 3.2 MB chunks).
// 4 lane-groups of 16 stripe the dest's edge list; 2 shfl_xor to combine.
__global__ void k_hop_gather(const int* __restrict__ rowptr, const float2* __restrict__ pack,
                             const float* __restrict__ dinv,
                             const unsigned short* __restrict__ Qin,
                             unsigned short* __restrict__ Qout) {
    int pass = blockIdx.x / HB;
    int wid = (blockIdx.x % HB) * 4 + (threadIdx.x >> 6);
    int lane = threadIdx.x & 63;
    int g = lane >> 4, j = lane & 15;
    const char* qc = (const char*)(Qin + (size_t)pass * (NN * 16));
    unsigned short* qo = Qout + (size_t)pass * (NN * 16);
    const unsigned long long* pk = (const unsigned long long*)pack;
    int beg = rowptr[wid], end = rowptr[wid + 1];
    float acc = 0.0f;
    if (g == 0) {
        float d = dinv[wid];
        acc = d * d * bf2f(*(const unsigned short*)(qc + wid * 32 + j * 2));
    }
    unsigned j2 = (unsigned)(j * 2);
    int e = beg + g;
    for (; e + 4 < end; e += 8) {
        unsigned long long w0 = __builtin_nontemporal_load(pk + e);
        unsigned long long w1 = __builtin_nontemporal_load(pk + e + 4);
        unsigned short q0 = *(const unsigned short*)(qc + ((unsigned)w0 + j2));
        unsigned short q1 = *(const unsigned short*)(qc + ((unsigned)w1 + j2));
        acc += __uint_as_float((unsigned)(w0 >> 32)) * bf2f(q0);
        acc += __uint_as_float((unsigned)(w1 >> 32)) * bf2f(q1);
    }
    for (; e < end; e += 4) {
        unsigned long long w = __builtin_nontemporal_load(pk + e);
        acc += __uint_as_float((unsigned)(w >> 32)) *
               bf2f(*(const unsigned short*)(qc + ((unsigned)w + j2)));
    }
    acc += __shfl_xor(acc, 16);
    acc += __shfl_xor(acc, 32);
    if (g == 0)
        __builtin_nontemporal_store(f2bf(acc), &qo[wid * 16 + j]);
}

// ---------------- pool: per-block partial[g][f] from chunked Q ----------------
__global__ __launch_bounds__(256) void k_pool(const unsigned short* __restrict__ Q,
                                              const float* __restrict__ x,
                                              float* __restrict__ partial) {
    __shared__ unsigned short qsh[NPASS * PT * 16];   // 8 KB (bf16, chunked)
    __shared__ float xs[PT * NF];                     // 32 KB
    int t = threadIdx.x;
    int f4 = (t & 31) << 2;
    int g0 = (t >> 5) << 3;
    int qch = g0 >> 4;            // chunk of this thread's 8 graphs
    int qof = g0 & 15;            // 0 or 8 within chunk
    float4 acc[8];
#pragma unroll
    for (int i = 0; i < 8; ++i) acc[i] = make_float4(0.f, 0.f, 0.f, 0.f);

    const int NT = (NN + PT - 1) / PT;   // 1563
    for (int tile = blockIdx.x; tile < NT; tile += GP) {
        int n0 = tile * PT;
        int nt = min(PT, NN - n0);
        const float4* X4 = (const float4*)(x + (size_t)n0 * NF);
        float4* xs4 = (float4*)xs;
#pragma unroll
        for (int c = 0; c < NPASS; ++c) {
            const uint4* Qc = (const uint4*)(Q + (size_t)c * (NN * 16) + (size_t)n0 * 16);
            uint4* qs4 = (uint4*)&qsh[c * PT * 16];
            for (int i = t; i < nt * 2; i += 256) qs4[i] = Qc[i];   // linear fill
        }
        for (int i = t; i < nt * (NF / 4); i += 256) xs4[i] = X4[i];
        __syncthreads();
        for (int n = 0; n < nt; ++n) {
            float4 xv = *(const float4*)&xs[n * NF + f4];
            uint4 qu = *(const uint4*)&qsh[qch * PT * 16 + n * 16 + qof];
            float qv[8];
            qv[0] = __uint_as_float(qu.x << 16);
            qv[1] = __uint_as_float(qu.x & 0xffff0000u);
            qv[2] = __uint_as_float(qu.y << 16);
            qv[3] = __uint_as_float(qu.y & 0xffff0000u);
            qv[4] = __uint_as_float(qu.z << 16);
            qv[5] = __uint_as_float(qu.z & 0xffff0000u);
            qv[6] = __uint_as_float(qu.w << 16);
            qv[7] = __uint_as_float(qu.w & 0xffff0000u);
#pragma unroll
            for (int i = 0; i < 8; ++i) {
                acc[i].x += qv[i] * xv.x;
                acc[i].y += qv[i] * xv.y;
                acc[i].z += qv[i] * xv.z;
                acc[i].w += qv[i] * xv.w;
            }
        }
        __syncthreads();
    }
    float* pb = partial + (size_t)blockIdx.x * (NG * NF);
#pragma unroll
    for (int i = 0; i < 8; ++i)
        *(float4*)&pb[(g0 + i) * NF + f4] = acc[i];
}

// ---------------- reduce GP partial slabs -> psum (8-way split-K) ----------------
__global__ void k_red(const float* __restrict__ partial, float* __restrict__ psum) {
    int gid = blockIdx.x * blockDim.x + threadIdx.x;   // 65536 threads
    int idx = gid & (NG * NF - 1);
    int j = gid >> 13;                                 // 0..7
    float acc = 0.0f;
    for (int b = j; b < GP; b += 8)
        acc += partial[(size_t)b * (NG * NF) + idx];
    atomicAdd(&psum[idx], acc);
}

// ---------------- final: fold both linears ----------------
__global__ void k_final(const float* __restrict__ psum, const float* __restrict__ cnt,
                        const float* __restrict__ Wc, const float* __restrict__ bc,
                        const float* __restrict__ Wl, const float* __restrict__ bl,
                        float* __restrict__ out) {
    __shared__ float M[NP * NH];
    __shared__ float bias[NP];
    int t = threadIdx.x;
    for (int idx = t; idx < NP * NH; idx += 256) {
        int p = idx >> 7, f = idx & 127;
        float s = 0.0f;
        for (int h = 0; h < NH; ++h) s += Wl[p * NH + h] * Wc[h * NF + f];
        M[idx] = s;
    }
    if (t < NP) {
        float s = bl[t];
        for (int h = 0; h < NH; ++h) s += Wl[t * NH + h] * bc[h];
        bias[t] = s;
    }
    __syncthreads();
    for (int idx = t; idx < NG * NP; idx += 256) {
        int g = idx >> 3, p = idx & 7;
        float inv = 1.0f / fmaxf(cnt[g], 1.0f);
        float s = 0.0f;
        for (int f = 0; f < NF; ++f) s += psum[g * NF + f] * M[p * NH + f];
        out[idx] = s * inv + bias[p];
    }
}

extern "C" void kernel_launch(void* const* d_in, const int* in_sizes, int n_in,
                              void* d_out, int out_size, void* d_ws, size_t ws_size,
                              hipStream_t stream) {
    const float* x     = (const float*)d_in[0];
    const int*   ei    = (const int*)d_in[1];
    const float* ea    = (const float*)d_in[2];
    const int*   batch = (const int*)d_in[3];
    const float* Wc    = (const float*)d_in[4];
    const float* bc    = (const float*)d_in[5];
    const float* Wl    = (const float*)d_in[6];
    const float* bl    = (const float*)d_in[7];
    const int* row = ei;           // edge_index[0]
    const int* col = ei + NE;      // edge_index[1]
    float* out = (float*)d_out;

    // ---- workspace (~77.7 MB footprint, all segments 16 B aligned) ----
    // Scan scratch aliases pack (dead before k_sort writes pack).
    // Qa (chunked bf16) = first half of H block (H dead after k_sort).
    // partial (GP*8192 f32 = 33.6 MB) = Qb half + Hd (both dead before k_pool).
    float* ws     = (float*)d_ws;
    float*  dinv   = ws;                          // NN floats
    int*    rowptr = (int*)(dinv + NN);           // NN+4 ints
    float*  cnt    = (float*)(rowptr + NN + 4);   // NG
    float*  psum   = cnt + NG;                    // NG*NH
    float2* pack   = (float2*)(psum + NG * NH);   // NE float2 (25.6 MB)
    unsigned* H    = (unsigned*)(pack + NE);      // NW*NN u32 (25.6 MB)
    float*    Hd   = (float*)(H + (size_t)NW * NN); // NW*NN f32 (25.6 MB)
    unsigned short* Qa = (unsigned short*)H;              // 4 chunks [NN][16] bf16
    unsigned short* Qb = Qa + (size_t)NN * NG;            // 4 chunks [NN][16] bf16
    float* partial = (float*)Qb;                  // GP*NG*NF f32 (spans Qb+Hd)
    int* rcnt = (int*)pack;                       // scan scratch (aliases pack)
    int* px   = rcnt + SCAN_NBLK * SCAN_B;
    int* bsum = px + SCAN_NBLK * SCAN_B;
    int* bofs = bsum + SCAN_NBLK;

    const int B = 256;
    int gN  = (NN + B - 1) / B;                          // 391
    int gCW = NC * NW;                                   // 448
    int gW  = (int)(((long long)NN * 64 + B - 1) / B);   // 25000

    k_init<<<(NG * NH + B - 1) / B, B, 0, stream>>>(cnt, psum);
    k_hist<<<gCW, B, 0, stream>>>(row, H);
    k_deg_hist<<<gCW, B, 0, stream>>>(col, ea, Hd);
    k_cnt<<<gN, B, 0, stream>>>(batch, cnt);
    k_reduce<<<gN, B, 0, stream>>>(H, Hd, rcnt, dinv);

    k_scan1<<<SCAN_NBLK, SCAN_B, 0, stream>>>(rcnt, px, bsum);
    k_scan2<<<1, 64, 0, stream>>>(bsum, bofs);
    k_scan3<<<(NN + 1 + SCAN_B - 1) / SCAN_B, SCAN_B, 0, stream>>>(px, bofs, rowptr);
    k_base<<<gN, B, 0, stream>>>(rowptr, H);
    k_sort<<<gCW, B, 0, stream>>>(row, col, ea, H, dinv, pack);

    // NOTE: k_q1_gather overwrites the H region (as Qa) — H is dead after k_sort.
    k_q1_gather<<<gW, B, 0, stream>>>(rowptr, pack, batch, dinv, Qa);
    k_hop_gather<<<NPASS * HB, B, 0, stream>>>(rowptr, pack, dinv, Qa, Qb);
    k_hop_gather<<<NPASS * HB, B, 0, stream>>>(rowptr, pack, dinv, Qb, Qa);

    // NOTE: k_pool writes partial over Qb+Hd (dead); reads Qa (live).
    k_pool<<<GP, B, 0, stream>>>(Qa, x, partial);
    k_red<<<256, B, 0, stream>>>(partial, psum);
    k_final<<<1, B, 0, stream>>>(psum, cnt, Wc, bc, Wl, bl, out);
}